// Round 2
// baseline (254.828 us; speedup 1.0000x reference)
//
#include <hip/hip_runtime.h>

typedef __bf16 bf16x8 __attribute__((ext_vector_type(8)));
typedef float floatx4 __attribute__((ext_vector_type(4)));

__device__ __forceinline__ ushort f2bf(float f) {
  union { float f; unsigned u; } a; a.f = f;
  unsigned u = a.u;
  unsigned r = (u + 0x7FFFu + ((u >> 16) & 1u)) >> 16;
  return (ushort)r;
}

// ---------------- conversions ----------------
__global__ __launch_bounds__(256) void cvt_bf16_kernel(const float* __restrict__ src,
                                                       ushort* __restrict__ dst, int n4) {
  int i = blockIdx.x * 256 + threadIdx.x;
  if (i >= n4) return;
  float4 v = ((const float4*)src)[i];
  ushort4 o;
  o.x = f2bf(v.x); o.y = f2bf(v.y); o.z = f2bf(v.z); o.w = f2bf(v.w);
  ((ushort4*)dst)[i] = o;
}

// W: K x N (f32, row-major)  ->  WT: N x K (bf16, row-major), scaled
__global__ __launch_bounds__(256) void conv_T_kernel(const float* __restrict__ W,
                                                     ushort* __restrict__ WT,
                                                     int K, int N, float scale) {
  __shared__ float tile[32][33];
  int n0 = blockIdx.x * 32, k0 = blockIdx.y * 32;
  int xi = threadIdx.x & 31, yi = threadIdx.x >> 5;  // yi 0..7
  #pragma unroll
  for (int i = 0; i < 32; i += 8)
    tile[yi + i][xi] = W[(size_t)(k0 + yi + i) * N + n0 + xi];
  __syncthreads();
  #pragma unroll
  for (int i = 0; i < 32; i += 8)
    WT[(size_t)(n0 + yi + i) * K + k0 + xi] = f2bf(tile[xi][yi + i] * scale);
}

// ---------------- GEMM: C(MxN,f32) = A(MxK,bf16) * BT(NxK,bf16)^T ----------------
__global__ __launch_bounds__(256) void gemm_bf16_kernel(const ushort* __restrict__ A,
                                                        const ushort* __restrict__ BT,
                                                        float* __restrict__ C,
                                                        int M, int N, int K) {
  __shared__ __align__(16) ushort As[128][72];
  __shared__ __align__(16) ushort Bs[128][72];
  int tid = threadIdx.x;
  int lane = tid & 63, wid = tid >> 6;
  int wr = wid >> 1, wc = wid & 1;
  int m0 = blockIdx.x * 128, n0 = blockIdx.y * 128;
  int row = lane & 15, kseg = (lane >> 4) << 3;

  floatx4 acc[4][4];
  #pragma unroll
  for (int r = 0; r < 4; r++)
    #pragma unroll
    for (int c = 0; c < 4; c++)
      acc[r][c] = (floatx4){0.f, 0.f, 0.f, 0.f};

  int sm = tid >> 1;
  int sh = (tid & 1) * 32;
  const ushort* ag = A + (size_t)(m0 + sm) * K + sh;
  const ushort* bg = BT + (size_t)(n0 + sm) * K + sh;

  for (int k0 = 0; k0 < K; k0 += 64) {
    const float4* agv = (const float4*)(ag + k0);
    const float4* bgv = (const float4*)(bg + k0);
    float4 a0 = agv[0], a1 = agv[1], a2 = agv[2], a3 = agv[3];
    float4 b0 = bgv[0], b1 = bgv[1], b2 = bgv[2], b3 = bgv[3];
    __syncthreads();
    *(float4*)&As[sm][sh + 0]  = a0;
    *(float4*)&As[sm][sh + 8]  = a1;
    *(float4*)&As[sm][sh + 16] = a2;
    *(float4*)&As[sm][sh + 24] = a3;
    *(float4*)&Bs[sm][sh + 0]  = b0;
    *(float4*)&Bs[sm][sh + 8]  = b1;
    *(float4*)&Bs[sm][sh + 16] = b2;
    *(float4*)&Bs[sm][sh + 24] = b3;
    __syncthreads();
    #pragma unroll
    for (int kk = 0; kk < 64; kk += 32) {
      bf16x8 av[4], bv[4];
      #pragma unroll
      for (int r = 0; r < 4; r++)
        av[r] = *(const bf16x8*)&As[wr * 64 + r * 16 + row][kk + kseg];
      #pragma unroll
      for (int c = 0; c < 4; c++)
        bv[c] = *(const bf16x8*)&Bs[wc * 64 + c * 16 + row][kk + kseg];
      #pragma unroll
      for (int r = 0; r < 4; r++)
        #pragma unroll
        for (int c = 0; c < 4; c++)
          acc[r][c] = __builtin_amdgcn_mfma_f32_16x16x32_bf16(av[r], bv[c], acc[r][c], 0, 0, 0);
    }
  }

  int r4 = (lane >> 4) << 2;
  #pragma unroll
  for (int r = 0; r < 4; r++)
    #pragma unroll
    for (int c = 0; c < 4; c++) {
      int crow = m0 + wr * 64 + r * 16 + r4;
      int ccol = n0 + wc * 64 + c * 16 + (lane & 15);
      #pragma unroll
      for (int i = 0; i < 4; i++)
        C[(size_t)(crow + i) * N + ccol] = acc[r][c][i];
    }
}

// ---------------- decay gate (full f32) ----------------
__global__ __launch_bounds__(256) void gate_kernel(const float* __restrict__ x,
                                                   const float* __restrict__ Wg1,
                                                   const float* __restrict__ Wg2,
                                                   float* __restrict__ gamma) {
  int rowi = blockIdx.x;          // b*1024 + l
  int b = rowi >> 10, l = rowi & 1023;
  int tid = threadIdx.x;
  __shared__ float part[16][17];
  __shared__ float tsh[16];

  {
    int j = tid & 15, slice = tid >> 4;
    const float* xr = x + (size_t)rowi * 1024 + slice * 64;
    float p = 0.f;
    #pragma unroll 4
    for (int kk = 0; kk < 64; kk++)
      p += xr[kk] * Wg1[(size_t)(slice * 64 + kk) * 16 + j];
    part[slice][j] = p;
  }
  __syncthreads();
  if (tid < 16) {
    float s = 0.f;
    #pragma unroll
    for (int i = 0; i < 16; i++) s += part[i][tid];
    tsh[tid] = s;
  }
  __syncthreads();

  float ls0, ls1;
  {
    int n = tid;
    float kg = 0.f;
    #pragma unroll
    for (int j = 0; j < 16; j++) kg += tsh[j] * Wg2[j * 512 + n];
    ls0 = (kg >= 0.f) ? -log1pf(expf(-kg)) : (kg - log1pf(expf(kg)));
  }
  {
    int n = tid + 256;
    float kg = 0.f;
    #pragma unroll
    for (int j = 0; j < 16; j++) kg += tsh[j] * Wg2[j * 512 + n];
    ls1 = (kg >= 0.f) ? -log1pf(expf(-kg)) : (kg - log1pf(expf(kg)));
  }
  #pragma unroll
  for (int m = 32; m >= 1; m >>= 1) {
    ls0 += __shfl_xor(ls0, m);
    ls1 += __shfl_xor(ls1, m);
  }
  if ((tid & 63) == 0) {
    int w = tid >> 6;
    gamma[(size_t)(b * 8 + w) * 1024 + l]       = expf(ls0 * (1.f / 1024.f)) + 1e-6f;
    gamma[(size_t)(b * 8 + w + 4) * 1024 + l]   = expf(ls1 * (1.f / 1024.f)) + 1e-6f;
  }
}

// ---------------- within-chunk prefix products ----------------
// grid 256 (bh*16+c), 64 threads
__global__ __launch_bounds__(64) void prefix_kernel(const float* __restrict__ gamma,
                                                    float* __restrict__ af,
                                                    float* __restrict__ Atot) {
  int blk = blockIdx.x;
  int bh = blk >> 4, c = blk & 15;
  int lane = threadIdx.x;
  float g = gamma[(size_t)bh * 1024 + c * 64 + lane];
  #pragma unroll
  for (int m = 1; m < 64; m <<= 1) {
    float o = __shfl_up(g, m);
    if (lane >= m) g *= o;
  }
  af[(size_t)bh * 1024 + c * 64 + lane] = g;
  if (lane == 63) Atot[blk] = g;
}

// ---------------- per-chunk T = K_hat^T V  (64d x 128e, f32) ----------------
// grid (16 chunks, 16 bh), 256 threads
__global__ __launch_bounds__(256) void chunk_T_kernel(const float* __restrict__ Y,
                                                      const float* __restrict__ af,
                                                      const float* __restrict__ Atot,
                                                      float* __restrict__ T) {
  int c = blockIdx.x, bh = blockIdx.y;
  int b = bh >> 3, h = bh & 7;
  int tid = threadIdx.x;

  __shared__ __align__(16) float Kh[64][64];
  __shared__ __align__(16) float Vv[64][128];

  float Ac = Atot[bh * 16 + c];
  const float* Yb = Y + (size_t)(b * 1024 + c * 64) * 3072;

  #pragma unroll
  for (int i = 0; i < 4; i++) {
    int idx = tid + i * 256;
    int s = idx >> 4, d4 = (idx & 15) * 4;
    float ratio = Ac / af[(size_t)bh * 1024 + c * 64 + s];
    floatx4 k4 = *(const floatx4*)(Yb + (size_t)s * 3072 + 512 + h * 64 + d4);
    *(floatx4*)&Kh[s][d4] = k4 * ratio;
  }
  #pragma unroll
  for (int i = 0; i < 8; i++) {
    int idx = tid + i * 256;
    int s = idx >> 5, e4 = (idx & 31) * 4;
    *(floatx4*)&Vv[s][e4] = *(const floatx4*)(Yb + (size_t)s * 3072 + 1024 + h * 128 + e4);
  }
  __syncthreads();

  int d0 = (tid >> 4) * 4, e0 = (tid & 15) * 8;
  floatx4 acc[4][2];
  #pragma unroll
  for (int i = 0; i < 4; i++) { acc[i][0] = 0.f; acc[i][1] = 0.f; }

  for (int s = 0; s < 64; s += 4) {
    floatx4 kv[4];
    #pragma unroll
    for (int k = 0; k < 4; k++) kv[k] = *(floatx4*)&Kh[s + k][d0];
    #pragma unroll
    for (int k = 0; k < 4; k++) {
      floatx4 v0 = *(floatx4*)&Vv[s + k][e0];
      floatx4 v1 = *(floatx4*)&Vv[s + k][e0 + 4];
      #pragma unroll
      for (int i = 0; i < 4; i++) {
        acc[i][0] += kv[k][i] * v0;
        acc[i][1] += kv[k][i] * v1;
      }
    }
  }

  float* To = T + (size_t)(bh * 16 + c) * 8192;
  #pragma unroll
  for (int i = 0; i < 4; i++) {
    *(floatx4*)(To + (size_t)(d0 + i) * 128 + e0)     = acc[i][0];
    *(floatx4*)(To + (size_t)(d0 + i) * 128 + e0 + 4) = acc[i][1];
  }
}

// ---------------- serial inter-chunk state recurrence ----------------
// grid 16 (bh), 512 threads; S held in registers (4 floatx4/thread)
__global__ __launch_bounds__(512) void state_kernel(const float* __restrict__ T,
                                                    const float* __restrict__ Atot,
                                                    float* __restrict__ Sin) {
  int bh = blockIdx.x;
  int tid = threadIdx.x;
  floatx4 S[4];
  #pragma unroll
  for (int i = 0; i < 4; i++) S[i] = 0.f;

  for (int c = 0; c < 16; c++) {
    float A = Atot[bh * 16 + c];
    const floatx4* Tc = (const floatx4*)(T + (size_t)(bh * 16 + c) * 8192);
    floatx4* Sc = (floatx4*)(Sin + (size_t)(bh * 16 + c) * 8192);
    #pragma unroll
    for (int i = 0; i < 4; i++) {
      int idx = tid + i * 512;
      Sc[idx] = S[i];
      S[i] = A * S[i] + Tc[idx];
    }
  }
}

// ---------------- per-chunk output + LN + silu gate -> bf16 ----------------
// grid (16 chunks, 16 bh), 256 threads; LDS = exactly 64KB
__global__ __launch_bounds__(256) void out_chunk_kernel(const float* __restrict__ Y,
                                                        const float* __restrict__ af,
                                                        const float* __restrict__ Sin,
                                                        const float* __restrict__ bgp,
                                                        ushort* __restrict__ gout) {
  int c = blockIdx.x, bh = blockIdx.y;
  int b = bh >> 3, h = bh & 7;
  int tid = threadIdx.x;

  __shared__ __align__(16) float Ms[64][128];  // [Qt | Kt], later V
  __shared__ __align__(16) float Ns[64][128];  // S_in, later P

  const float* Yb = Y + (size_t)(b * 1024 + c * 64) * 3072;
  const float* afc = af + (size_t)bh * 1024 + c * 64;
  const float* Sc = Sin + (size_t)(bh * 16 + c) * 8192;

  // ph1: load Qt (a_t*q) -> Ms[:, 0:64], Kt (k/a_s) -> Ms[:, 64:128], S_in -> Ns
  #pragma unroll
  for (int i = 0; i < 4; i++) {
    int idx = tid + i * 256;
    int t = idx >> 4, d4 = (idx & 15) * 4;
    float at = afc[t];
    floatx4 q4 = *(const floatx4*)(Yb + (size_t)t * 3072 + h * 64 + d4);
    floatx4 k4 = *(const floatx4*)(Yb + (size_t)t * 3072 + 512 + h * 64 + d4);
    *(floatx4*)&Ms[t][d4]      = q4 * at;
    *(floatx4*)&Ms[t][64 + d4] = k4 * (1.0f / at);
  }
  #pragma unroll
  for (int i = 0; i < 8; i++) {
    int idx = tid + i * 256;
    int d = idx >> 5, e4 = (idx & 31) * 4;
    *(floatx4*)&Ns[d][e4] = *(const floatx4*)(Sc + (size_t)d * 128 + e4);
  }
  __syncthreads();

  // ph2: acc = Qt @ S_in   (4t x 8e per thread)
  int t0 = (tid >> 4) * 4, e0 = (tid & 15) * 8;
  int s0 = (tid & 15) * 4;
  floatx4 acc[4][2];
  #pragma unroll
  for (int i = 0; i < 4; i++) { acc[i][0] = 0.f; acc[i][1] = 0.f; }

  for (int d = 0; d < 64; d += 4) {
    floatx4 mv[4];
    #pragma unroll
    for (int i = 0; i < 4; i++) mv[i] = *(floatx4*)&Ms[t0 + i][d];
    #pragma unroll
    for (int k = 0; k < 4; k++) {
      floatx4 n0 = *(floatx4*)&Ns[d + k][e0];
      floatx4 n1 = *(floatx4*)&Ns[d + k][e0 + 4];
      #pragma unroll
      for (int i = 0; i < 4; i++) {
        acc[i][0] += mv[i][k] * n0;
        acc[i][1] += mv[i][k] * n1;
      }
    }
  }
  __syncthreads();

  // ph3: P[t][s] = (s<=t) ? Qt[t]·Kt[s] : 0  -> Ns[t][s] (s<64)
  {
    float p[4][4];
    #pragma unroll
    for (int i = 0; i < 4; i++)
      #pragma unroll
      for (int j = 0; j < 4; j++) p[i][j] = 0.f;
    for (int d = 0; d < 64; d += 4) {
      floatx4 qa[4], kb[4];
      #pragma unroll
      for (int i = 0; i < 4; i++) qa[i] = *(floatx4*)&Ms[t0 + i][d];
      #pragma unroll
      for (int j = 0; j < 4; j++) kb[j] = *(floatx4*)&Ms[s0 + j][64 + d];
      #pragma unroll
      for (int i = 0; i < 4; i++)
        #pragma unroll
        for (int j = 0; j < 4; j++)
          p[i][j] += qa[i][0] * kb[j][0] + qa[i][1] * kb[j][1] +
                     qa[i][2] * kb[j][2] + qa[i][3] * kb[j][3];
    }
    __syncthreads();  // everyone done reading S_in region? (done in ph2) & Ms reads done
    #pragma unroll
    for (int i = 0; i < 4; i++)
      #pragma unroll
      for (int j = 0; j < 4; j++)
        Ns[t0 + i][s0 + j] = (s0 + j <= t0 + i) ? p[i][j] : 0.f;
  }
  __syncthreads();

  // ph4a: load V -> Ms (overwrite)
  #pragma unroll
  for (int i = 0; i < 8; i++) {
    int idx = tid + i * 256;
    int s = idx >> 5, e4 = (idx & 31) * 4;
    *(floatx4*)&Ms[s][e4] = *(const floatx4*)(Yb + (size_t)s * 3072 + 1024 + h * 128 + e4);
  }
  __syncthreads();

  // ph4b: acc += P @ V
  for (int s = 0; s < 64; s += 4) {
    floatx4 pv[4];
    #pragma unroll
    for (int i = 0; i < 4; i++) pv[i] = *(floatx4*)&Ns[t0 + i][s];
    #pragma unroll
    for (int k = 0; k < 4; k++) {
      floatx4 v0 = *(floatx4*)&Ms[s + k][e0];
      floatx4 v1 = *(floatx4*)&Ms[s + k][e0 + 4];
      #pragma unroll
      for (int i = 0; i < 4; i++) {
        acc[i][0] += pv[i][k] * v0;
        acc[i][1] += pv[i][k] * v1;
      }
    }
  }

  // LN (over 128 e, threads sharing t0 are 16 consecutive lanes) + silu gate
  #pragma unroll
  for (int i = 0; i < 4; i++) {
    float s1 = 0.f, s2 = 0.f;
    #pragma unroll
    for (int j = 0; j < 4; j++) {
      s1 += acc[i][0][j] + acc[i][1][j];
      s2 += acc[i][0][j] * acc[i][0][j] + acc[i][1][j] * acc[i][1][j];
    }
    #pragma unroll
    for (int m = 8; m >= 1; m >>= 1) {
      s1 += __shfl_xor(s1, m);
      s2 += __shfl_xor(s2, m);
    }
    float mu = s1 * (1.f / 128.f);
    float var = s2 * (1.f / 128.f) - mu * mu;
    float rs = rsqrtf(var + 1e-5f);

    int rowg = b * 1024 + c * 64 + t0 + i;
    floatx4 z0 = *(const floatx4*)(Yb + (size_t)(c ? (t0 + i) : (t0 + i)) * 3072 + 2048 + h * 128 + e0);
    floatx4 z1 = *(const floatx4*)(Yb + (size_t)(t0 + i) * 3072 + 2048 + h * 128 + e0 + 4);
    floatx4 bg0 = *(const floatx4*)(bgp + h * 128 + e0);
    floatx4 bg1 = *(const floatx4*)(bgp + h * 128 + e0 + 4);
    ushort o[8];
    #pragma unroll
    for (int j = 0; j < 4; j++) {
      float y = (acc[i][0][j] - mu) * rs;
      float z = z0[j] + bg0[j];
      float gv = z / (1.f + expf(-z));
      o[j] = f2bf(y * gv);
    }
    #pragma unroll
    for (int j = 0; j < 4; j++) {
      float y = (acc[i][1][j] - mu) * rs;
      float z = z1[j] + bg1[j];
      float gv = z / (1.f + expf(-z));
      o[4 + j] = f2bf(y * gv);
    }
    ushort* go = gout + (size_t)rowg * 1024 + h * 128 + e0;
    *(ushort4*)(go)     = *(ushort4*)&o[0];
    *(ushort4*)(go + 4) = *(ushort4*)&o[4];
  }
}

// ---------------- launch ----------------
extern "C" void kernel_launch(void* const* d_in, const int* in_sizes, int n_in,
                              void* d_out, int out_size, void* d_ws, size_t ws_size,
                              hipStream_t stream) {
  const float* x    = (const float*)d_in[0];
  const float* Wq   = (const float*)d_in[1];
  const float* Wk   = (const float*)d_in[2];
  const float* Wg1  = (const float*)d_in[3];
  const float* Wg2  = (const float*)d_in[4];
  const float* Wv   = (const float*)d_in[5];
  const float* Wgp  = (const float*)d_in[6];
  const float* bgp  = (const float*)d_in[7];
  const float* Wout = (const float*)d_in[8];
  float* out = (float*)d_out;

  char* ws = (char*)d_ws;
  float*  Y      = (float*)(ws + 0);                 // 2048*3072*4 = 25165824
  float*  T      = (float*)(ws + 25165824);          // 16*16*8192*4 = 8388608
  float*  Sin    = (float*)(ws + 33554432);          // 8388608
  float*  gamma  = (float*)(ws + 41943040);          // 65536
  float*  af     = (float*)(ws + 42008576);          // 65536
  float*  Atot   = (float*)(ws + 42074112);          // 1024
  ushort* xb     = (ushort*)(ws + 42075136);         // 4194304
  ushort* WcatT  = (ushort*)(ws + 46269440);         // 6291456
  ushort* WoutT  = (ushort*)(ws + 52560896);         // 2097152
  ushort* gout   = (ushort*)(ws + 54658048);         // 4194304
  // total 58852352 bytes

  cvt_bf16_kernel<<<2048, 256, 0, stream>>>(x, xb, 2048 * 1024 / 4);
  conv_T_kernel<<<dim3(16, 32), 256, 0, stream>>>(Wq,  WcatT + (size_t)0 * 1024,    1024, 512,  1.0f);
  conv_T_kernel<<<dim3(16, 32), 256, 0, stream>>>(Wk,  WcatT + (size_t)512 * 1024,  1024, 512,  0.125f);
  conv_T_kernel<<<dim3(32, 32), 256, 0, stream>>>(Wv,  WcatT + (size_t)1024 * 1024, 1024, 1024, 1.0f);
  conv_T_kernel<<<dim3(32, 32), 256, 0, stream>>>(Wgp, WcatT + (size_t)2048 * 1024, 1024, 1024, 1.0f);
  conv_T_kernel<<<dim3(32, 32), 256, 0, stream>>>(Wout, WoutT,                      1024, 1024, 1.0f);

  gate_kernel<<<2048, 256, 0, stream>>>(x, Wg1, Wg2, gamma);

  // fused projections: Y = xb @ [Wq|Wk*s|Wv|Wgp]
  gemm_bf16_kernel<<<dim3(16, 24), 256, 0, stream>>>(xb, WcatT, Y, 2048, 3072, 1024);

  // chunked scan
  prefix_kernel<<<256, 64, 0, stream>>>(gamma, af, Atot);
  chunk_T_kernel<<<dim3(16, 16), 256, 0, stream>>>(Y, af, Atot, T);
  state_kernel<<<16, 512, 0, stream>>>(T, Atot, Sin);
  out_chunk_kernel<<<dim3(16, 16), 256, 0, stream>>>(Y, af, Sin, bgp, gout);

  // output projection
  gemm_bf16_kernel<<<dim3(16, 8), 256, 0, stream>>>(gout, WoutT, out, 2048, 1024, 1024);
}

// Round 3
// 113.675 us; speedup vs baseline: 2.2417x; 2.2417x over previous
//
#include <hip/hip_runtime.h>

typedef __bf16 bf16x8 __attribute__((ext_vector_type(8)));
typedef float floatx4 __attribute__((ext_vector_type(4)));

__device__ __forceinline__ ushort f2bf(float f) {
  union { float f; unsigned u; } a; a.f = f;
  unsigned u = a.u;
  unsigned r = (u + 0x7FFFu + ((u >> 16) & 1u)) >> 16;
  return (ushort)r;
}

// swizzled index helpers (element index in, element index out)
#define SWZH(row, col, stride) ((((row) * (stride)) + (col)) ^ (((row) & 7) << 3))  // ushort tiles
#define SWZF(row, col, stride) ((((row) * (stride)) + (col)) ^ (((row) & 7) << 2))  // f32 tiles

// ---------------- conversions ----------------
__global__ __launch_bounds__(256) void cvt_bf16_kernel(const float* __restrict__ src,
                                                       ushort* __restrict__ dst, int n4) {
  int i = blockIdx.x * 256 + threadIdx.x;
  if (i >= n4) return;
  float4 v = ((const float4*)src)[i];
  ushort4 o;
  o.x = f2bf(v.x); o.y = f2bf(v.y); o.z = f2bf(v.z); o.w = f2bf(v.w);
  ((ushort4*)dst)[i] = o;
}

// W: K x N (f32, row-major)  ->  WT: N x K (bf16, row-major), scaled
__global__ __launch_bounds__(256) void conv_T_kernel(const float* __restrict__ W,
                                                     ushort* __restrict__ WT,
                                                     int K, int N, float scale) {
  __shared__ float tile[32][33];
  int n0 = blockIdx.x * 32, k0 = blockIdx.y * 32;
  int xi = threadIdx.x & 31, yi = threadIdx.x >> 5;
  #pragma unroll
  for (int i = 0; i < 32; i += 8)
    tile[yi + i][xi] = W[(size_t)(k0 + yi + i) * N + n0 + xi];
  __syncthreads();
  #pragma unroll
  for (int i = 0; i < 32; i += 8)
    WT[(size_t)(n0 + yi + i) * K + k0 + xi] = f2bf(tile[xi][yi + i] * scale);
}

// ---------------- GEMM: C(MxN,f32) = A(MxK,bf16) * BT(NxK,bf16)^T ----------------
__global__ __launch_bounds__(256) void gemm_bf16_kernel(const ushort* __restrict__ A,
                                                        const ushort* __restrict__ BT,
                                                        float* __restrict__ C,
                                                        int M, int N, int K) {
  __shared__ __align__(16) ushort As[128][72];
  __shared__ __align__(16) ushort Bs[128][72];
  int tid = threadIdx.x;
  int lane = tid & 63, wid = tid >> 6;
  int wr = wid >> 1, wc = wid & 1;
  int m0 = blockIdx.x * 128, n0 = blockIdx.y * 128;
  int row = lane & 15, kseg = (lane >> 4) << 3;

  floatx4 acc[4][4];
  #pragma unroll
  for (int r = 0; r < 4; r++)
    #pragma unroll
    for (int c = 0; c < 4; c++)
      acc[r][c] = (floatx4){0.f, 0.f, 0.f, 0.f};

  int sm = tid >> 1;
  int sh = (tid & 1) * 32;
  const ushort* ag = A + (size_t)(m0 + sm) * K + sh;
  const ushort* bg = BT + (size_t)(n0 + sm) * K + sh;

  for (int k0 = 0; k0 < K; k0 += 64) {
    const float4* agv = (const float4*)(ag + k0);
    const float4* bgv = (const float4*)(bg + k0);
    float4 a0 = agv[0], a1 = agv[1], a2 = agv[2], a3 = agv[3];
    float4 b0 = bgv[0], b1 = bgv[1], b2 = bgv[2], b3 = bgv[3];
    __syncthreads();
    *(float4*)&As[sm][sh + 0]  = a0;
    *(float4*)&As[sm][sh + 8]  = a1;
    *(float4*)&As[sm][sh + 16] = a2;
    *(float4*)&As[sm][sh + 24] = a3;
    *(float4*)&Bs[sm][sh + 0]  = b0;
    *(float4*)&Bs[sm][sh + 8]  = b1;
    *(float4*)&Bs[sm][sh + 16] = b2;
    *(float4*)&Bs[sm][sh + 24] = b3;
    __syncthreads();
    #pragma unroll
    for (int kk = 0; kk < 64; kk += 32) {
      bf16x8 av[4], bv[4];
      #pragma unroll
      for (int r = 0; r < 4; r++)
        av[r] = *(const bf16x8*)&As[wr * 64 + r * 16 + row][kk + kseg];
      #pragma unroll
      for (int c = 0; c < 4; c++)
        bv[c] = *(const bf16x8*)&Bs[wc * 64 + c * 16 + row][kk + kseg];
      #pragma unroll
      for (int r = 0; r < 4; r++)
        #pragma unroll
        for (int c = 0; c < 4; c++)
          acc[r][c] = __builtin_amdgcn_mfma_f32_16x16x32_bf16(av[r], bv[c], acc[r][c], 0, 0, 0);
    }
  }

  int r4 = (lane >> 4) << 2;
  #pragma unroll
  for (int r = 0; r < 4; r++)
    #pragma unroll
    for (int c = 0; c < 4; c++) {
      int crow = m0 + wr * 64 + r * 16 + r4;
      int ccol = n0 + wc * 64 + c * 16 + (lane & 15);
      #pragma unroll
      for (int i = 0; i < 4; i++)
        C[(size_t)(crow + i) * N + ccol] = acc[r][c][i];
    }
}

// ---------------- decay gate (full f32) ----------------
__global__ __launch_bounds__(256) void gate_kernel(const float* __restrict__ x,
                                                   const float* __restrict__ Wg1,
                                                   const float* __restrict__ Wg2,
                                                   float* __restrict__ gamma) {
  int rowi = blockIdx.x;          // b*1024 + l
  int b = rowi >> 10, l = rowi & 1023;
  int tid = threadIdx.x;
  __shared__ float part[16][17];
  __shared__ float tsh[16];

  {
    int j = tid & 15, slice = tid >> 4;
    const float* xr = x + (size_t)rowi * 1024 + slice * 64;
    float p = 0.f;
    #pragma unroll 4
    for (int kk = 0; kk < 64; kk++)
      p += xr[kk] * Wg1[(size_t)(slice * 64 + kk) * 16 + j];
    part[slice][j] = p;
  }
  __syncthreads();
  if (tid < 16) {
    float s = 0.f;
    #pragma unroll
    for (int i = 0; i < 16; i++) s += part[i][tid];
    tsh[tid] = s;
  }
  __syncthreads();

  float ls0, ls1;
  {
    int n = tid;
    float kg = 0.f;
    #pragma unroll
    for (int j = 0; j < 16; j++) kg += tsh[j] * Wg2[j * 512 + n];
    ls0 = (kg >= 0.f) ? -log1pf(expf(-kg)) : (kg - log1pf(expf(kg)));
  }
  {
    int n = tid + 256;
    float kg = 0.f;
    #pragma unroll
    for (int j = 0; j < 16; j++) kg += tsh[j] * Wg2[j * 512 + n];
    ls1 = (kg >= 0.f) ? -log1pf(expf(-kg)) : (kg - log1pf(expf(kg)));
  }
  #pragma unroll
  for (int m = 32; m >= 1; m >>= 1) {
    ls0 += __shfl_xor(ls0, m);
    ls1 += __shfl_xor(ls1, m);
  }
  if ((tid & 63) == 0) {
    int w = tid >> 6;
    gamma[(size_t)(b * 8 + w) * 1024 + l]       = expf(ls0 * (1.f / 1024.f)) + 1e-6f;
    gamma[(size_t)(b * 8 + w + 4) * 1024 + l]   = expf(ls1 * (1.f / 1024.f)) + 1e-6f;
  }
}

// ---------------- within-chunk prefix products ----------------
__global__ __launch_bounds__(64) void prefix_kernel(const float* __restrict__ gamma,
                                                    float* __restrict__ af,
                                                    float* __restrict__ Atot) {
  int blk = blockIdx.x;
  int bh = blk >> 4, c = blk & 15;
  int lane = threadIdx.x;
  float g = gamma[(size_t)bh * 1024 + c * 64 + lane];
  #pragma unroll
  for (int m = 1; m < 64; m <<= 1) {
    float o = __shfl_up(g, m);
    if (lane >= m) g *= o;
  }
  af[(size_t)bh * 1024 + c * 64 + lane] = g;
  if (lane == 63) Atot[blk] = g;
}

// ---------------- prep: bf16 operand arrays ----------------
// Qb[bh][l][d] = a_l * q ;  Kb[bh][l][d] = k ;  Ktb[bh][d][l] = (Ac/a_l) * k ;
// Vtb[bh][e][l] = v
__global__ __launch_bounds__(256) void prep_kernel(const float* __restrict__ Y,
                                                   const float* __restrict__ af,
                                                   const float* __restrict__ Atot,
                                                   ushort* __restrict__ Qb,
                                                   ushort* __restrict__ Kb,
                                                   ushort* __restrict__ Ktb,
                                                   ushort* __restrict__ Vtb) {
  int c = blockIdx.x, bh = blockIdx.y;
  int b = bh >> 3, h = bh & 7;
  int tid = threadIdx.x;
  __shared__ float a_sh[64];
  __shared__ __align__(16) float tile[64 * 68];

  float Ac = Atot[bh * 16 + c];
  if (tid < 64) a_sh[tid] = af[(size_t)bh * 1024 + c * 64 + tid];
  __syncthreads();

  const float* Yc = Y + (size_t)(b * 1024 + c * 64) * 3072;

  // Qb (scaled), Kb, and stage k tile for transpose
  #pragma unroll
  for (int i = 0; i < 4; i++) {
    int u = tid + i * 256;
    int row = u >> 4, col4 = u & 15;
    float at = a_sh[row];
    float4 q4 = *(const float4*)(Yc + (size_t)row * 3072 + h * 64 + col4 * 4);
    float4 k4 = *(const float4*)(Yc + (size_t)row * 3072 + 512 + h * 64 + col4 * 4);
    ushort4 qo, ko;
    qo.x = f2bf(q4.x * at); qo.y = f2bf(q4.y * at); qo.z = f2bf(q4.z * at); qo.w = f2bf(q4.w * at);
    ko.x = f2bf(k4.x); ko.y = f2bf(k4.y); ko.z = f2bf(k4.z); ko.w = f2bf(k4.w);
    *(ushort4*)(Qb + ((size_t)(bh * 1024 + c * 64 + row)) * 64 + col4 * 4) = qo;
    *(ushort4*)(Kb + ((size_t)(bh * 1024 + c * 64 + row)) * 64 + col4 * 4) = ko;
    *(float4*)&tile[row * 68 + col4 * 4] = k4;
  }
  __syncthreads();

  // Ktb: transposed, scaled by w_s = Ac / a_s
  {
    int d = tid & 63, sb = tid >> 6;
    ushort o[16];
    #pragma unroll
    for (int j = 0; j < 16; j++) {
      int s = sb * 16 + j;
      o[j] = f2bf(tile[s * 68 + d] * (Ac / a_sh[s]));
    }
    ushort* dst = Ktb + ((size_t)(bh * 64 + d)) * 1024 + c * 64 + sb * 16;
    *(uint4*)(dst) = *(uint4*)&o[0];
    *(uint4*)(dst + 8) = *(uint4*)&o[8];
  }

  // Vtb: two half passes through the tile
  #pragma unroll
  for (int p = 0; p < 2; p++) {
    __syncthreads();
    #pragma unroll
    for (int i = 0; i < 4; i++) {
      int u = tid + i * 256;
      int row = u >> 4, col4 = u & 15;
      *(float4*)&tile[row * 68 + col4 * 4] =
          *(const float4*)(Yc + (size_t)row * 3072 + 1024 + h * 128 + p * 64 + col4 * 4);
    }
    __syncthreads();
    {
      int el = tid & 63, sb = tid >> 6;
      ushort o[16];
      #pragma unroll
      for (int j = 0; j < 16; j++)
        o[j] = f2bf(tile[(sb * 16 + j) * 68 + el]);
      ushort* dst = Vtb + ((size_t)(bh * 128 + p * 64 + el)) * 1024 + c * 64 + sb * 16;
      *(uint4*)(dst) = *(uint4*)&o[0];
      *(uint4*)(dst + 8) = *(uint4*)&o[8];
    }
  }
}

// ---------------- per-chunk Tt[e][d] = sum_s V[s][e] * w_s k[s][d]  (MFMA) ----------------
__global__ __launch_bounds__(256) void chunk_T_kernel(const ushort* __restrict__ Ktb,
                                                      const ushort* __restrict__ Vtb,
                                                      float* __restrict__ Tt) {
  int c = blockIdx.x, bh = blockIdx.y;
  int tid = threadIdx.x;
  int lane = tid & 63, wid = tid >> 6;
  int col_l = lane & 15, kseg8 = (lane >> 4) * 8;
  int d0w = wid * 16;

  __shared__ __align__(16) ushort Kt[64 * 64];
  __shared__ __align__(16) ushort Vs[128 * 64];

  // stage (swizzled)
  #pragma unroll
  for (int i = 0; i < 2; i++) {
    int u = tid + i * 256;
    int row = u >> 3, col8 = u & 7;
    *(uint4*)&Kt[SWZH(row, col8 * 8, 64)] =
        *(const uint4*)(Ktb + ((size_t)(bh * 64 + row)) * 1024 + c * 64 + col8 * 8);
  }
  #pragma unroll
  for (int i = 0; i < 4; i++) {
    int u = tid + i * 256;
    int row = u >> 3, col8 = u & 7;
    *(uint4*)&Vs[SWZH(row, col8 * 8, 64)] =
        *(const uint4*)(Vtb + ((size_t)(bh * 128 + row)) * 1024 + c * 64 + col8 * 8);
  }
  __syncthreads();

  floatx4 acc[8];
  #pragma unroll
  for (int i = 0; i < 8; i++) acc[i] = (floatx4){0.f, 0.f, 0.f, 0.f};

  #pragma unroll
  for (int kk = 0; kk < 64; kk += 32) {
    bf16x8 kb = *(const bf16x8*)&Kt[SWZH(d0w + col_l, kk + kseg8, 64)];
    #pragma unroll
    for (int fe = 0; fe < 8; fe++) {
      bf16x8 vb = *(const bf16x8*)&Vs[SWZH(fe * 16 + col_l, kk + kseg8, 64)];
      acc[fe] = __builtin_amdgcn_mfma_f32_16x16x32_bf16(vb, kb, acc[fe], 0, 0, 0);
    }
  }

  float* To = Tt + (size_t)(bh * 16 + c) * 8192;
  #pragma unroll
  for (int fe = 0; fe < 8; fe++) {
    #pragma unroll
    for (int r = 0; r < 4; r++) {
      int e = fe * 16 + (lane >> 4) * 4 + r;
      To[(size_t)e * 64 + d0w + col_l] = acc[fe][r];
    }
  }
}

// ---------------- inter-chunk state recurrence (e-sliced) ----------------
// grid (16 eslice, 16 bh), 256 threads; each thread owns 2 state floats
__global__ __launch_bounds__(256) void state_kernel(const float* __restrict__ Tt,
                                                    const float* __restrict__ Atot,
                                                    ushort* __restrict__ Stb) {
  int es = blockIdx.x, bh = blockIdx.y;
  int tid = threadIdx.x;
  size_t off = (size_t)es * 512 + tid * 2;
  float2 S = {0.f, 0.f};
  for (int c = 0; c < 16; c++) {
    float A = Atot[bh * 16 + c];
    size_t base = (size_t)(bh * 16 + c) * 8192 + off;
    ushort2 o; o.x = f2bf(S.x); o.y = f2bf(S.y);
    *(ushort2*)(Stb + base) = o;
    float2 t = *(const float2*)(Tt + base);
    S.x = A * S.x + t.x;
    S.y = A * S.y + t.y;
  }
}

// ---------------- per-chunk output (MFMA) + LN + silu gate -> bf16 ----------------
__global__ __launch_bounds__(256) void out_chunk_kernel(const float* __restrict__ Y,
                                                        const float* __restrict__ af,
                                                        const ushort* __restrict__ Qb,
                                                        const ushort* __restrict__ Kb,
                                                        const ushort* __restrict__ Stb,
                                                        const ushort* __restrict__ Vtb,
                                                        const float* __restrict__ bgp,
                                                        ushort* __restrict__ gout) {
  int c = blockIdx.x, bh = blockIdx.y;
  int b = bh >> 3, h = bh & 7;
  int tid = threadIdx.x;
  int lane = tid & 63, wid = tid >> 6;
  int col_l = lane & 15, kseg8 = (lane >> 4) * 8;
  int t0w = wid * 16;

  __shared__ __align__(16) ushort Qs[64 * 64];
  __shared__ __align__(16) ushort Ks[64 * 64];
  __shared__ __align__(16) ushort Ss[128 * 64];
  __shared__ __align__(16) ushort Vs[128 * 64];
  __shared__ __align__(16) ushort Ps[64 * 64];
  __shared__ __align__(16) float zs[64 * 128];
  __shared__ float inva_sh[64];
  __shared__ float bsh[128];

  const float* Yc = Y + (size_t)(b * 1024 + c * 64) * 3072;

  // ---- stage ----
  #pragma unroll
  for (int i = 0; i < 2; i++) {
    int u = tid + i * 256;
    int row = u >> 3, col8 = u & 7;
    *(uint4*)&Qs[SWZH(row, col8 * 8, 64)] =
        *(const uint4*)(Qb + ((size_t)(bh * 1024 + c * 64 + row)) * 64 + col8 * 8);
    *(uint4*)&Ks[SWZH(row, col8 * 8, 64)] =
        *(const uint4*)(Kb + ((size_t)(bh * 1024 + c * 64 + row)) * 64 + col8 * 8);
  }
  #pragma unroll
  for (int i = 0; i < 4; i++) {
    int u = tid + i * 256;
    int row = u >> 3, col8 = u & 7;
    *(uint4*)&Ss[SWZH(row, col8 * 8, 64)] =
        *(const uint4*)(Stb + (size_t)(bh * 16 + c) * 8192 + (size_t)row * 64 + col8 * 8);
    *(uint4*)&Vs[SWZH(row, col8 * 8, 64)] =
        *(const uint4*)(Vtb + ((size_t)(bh * 128 + row)) * 1024 + c * 64 + col8 * 8);
  }
  #pragma unroll
  for (int i = 0; i < 8; i++) {
    int u = tid + i * 256;
    int row = u >> 5, col4 = u & 31;
    *(float4*)&zs[SWZF(row, col4 * 4, 128)] =
        *(const float4*)(Yc + (size_t)row * 3072 + 2048 + h * 128 + col4 * 4);
  }
  if (tid < 64) inva_sh[tid] = 1.f / af[(size_t)bh * 1024 + c * 64 + tid];
  if (tid < 128) bsh[tid] = bgp[h * 128 + tid];
  __syncthreads();

  // ---- ph1+ph2: P^T = K·Q^T ; acc = St·Q^T ----
  floatx4 pacc[4];
  floatx4 acc[8];
  #pragma unroll
  for (int i = 0; i < 4; i++) pacc[i] = (floatx4){0.f, 0.f, 0.f, 0.f};
  #pragma unroll
  for (int i = 0; i < 8; i++) acc[i] = (floatx4){0.f, 0.f, 0.f, 0.f};

  #pragma unroll
  for (int kk = 0; kk < 64; kk += 32) {
    bf16x8 qb = *(const bf16x8*)&Qs[SWZH(t0w + col_l, kk + kseg8, 64)];
    #pragma unroll
    for (int fs = 0; fs < 4; fs++) {
      bf16x8 kb = *(const bf16x8*)&Ks[SWZH(fs * 16 + col_l, kk + kseg8, 64)];
      pacc[fs] = __builtin_amdgcn_mfma_f32_16x16x32_bf16(kb, qb, pacc[fs], 0, 0, 0);
    }
    #pragma unroll
    for (int fe = 0; fe < 8; fe++) {
      bf16x8 sb = *(const bf16x8*)&Ss[SWZH(fe * 16 + col_l, kk + kseg8, 64)];
      acc[fe] = __builtin_amdgcn_mfma_f32_16x16x32_bf16(sb, qb, acc[fe], 0, 0, 0);
    }
  }

  // ---- ph3: mask + scale P, convert to bf16, store [t][s] ----
  int tl = t0w + col_l;
  #pragma unroll
  for (int fs = 0; fs < 4; fs++) {
    ushort o[4];
    #pragma unroll
    for (int r = 0; r < 4; r++) {
      int s = fs * 16 + (lane >> 4) * 4 + r;
      float pv = (s <= tl) ? pacc[fs][r] * inva_sh[s] : 0.f;
      o[r] = f2bf(pv);
    }
    int s0 = fs * 16 + (lane >> 4) * 4;
    *(ushort4*)&Ps[SWZH(tl, s0, 64)] = *(ushort4*)&o[0];
  }
  __syncthreads();

  // ---- ph4: acc += Vt·P^T  (Out^T[e][t]) ----
  #pragma unroll
  for (int kk = 0; kk < 64; kk += 32) {
    bf16x8 pb = *(const bf16x8*)&Ps[SWZH(t0w + col_l, kk + kseg8, 64)];
    #pragma unroll
    for (int fe = 0; fe < 8; fe++) {
      bf16x8 vb = *(const bf16x8*)&Vs[SWZH(fe * 16 + col_l, kk + kseg8, 64)];
      acc[fe] = __builtin_amdgcn_mfma_f32_16x16x32_bf16(vb, pb, acc[fe], 0, 0, 0);
    }
  }
  __syncthreads();   // Vs reads done everywhere; Gs will reuse Vs

  // ---- ph5: LN over e (reduce across lane>>4 groups) + silu gate ----
  float s1 = 0.f, s2 = 0.f;
  #pragma unroll
  for (int fe = 0; fe < 8; fe++)
    #pragma unroll
    for (int r = 0; r < 4; r++) {
      float v = acc[fe][r];
      s1 += v; s2 += v * v;
    }
  s1 += __shfl_xor(s1, 16); s2 += __shfl_xor(s2, 16);
  s1 += __shfl_xor(s1, 32); s2 += __shfl_xor(s2, 32);
  float mu = s1 * (1.f / 128.f);
  float var = s2 * (1.f / 128.f) - mu * mu;
  float rs = rsqrtf(var + 1e-5f);

  ushort* Gs = Vs;  // reuse
  #pragma unroll
  for (int fe = 0; fe < 8; fe++)
    #pragma unroll
    for (int r = 0; r < 4; r++) {
      int e = fe * 16 + (lane >> 4) * 4 + r;
      float y = (acc[fe][r] - mu) * rs;
      float z = zs[SWZF(tl, e, 128)] + bsh[e];
      float g = z / (1.f + expf(-z));
      Gs[SWZH(tl, e, 128)] = f2bf(y * g);
    }
  __syncthreads();

  // ---- ph6: coalesced store ----
  #pragma unroll
  for (int i = 0; i < 4; i++) {
    int u = tid + i * 256;
    int row = u >> 4, ch = u & 15;
    *(uint4*)(gout + ((size_t)(b * 1024 + c * 64 + row)) * 1024 + h * 128 + ch * 8) =
        *(uint4*)&Gs[SWZH(row, ch * 8, 128)];
  }
}

// ---------------- launch ----------------
extern "C" void kernel_launch(void* const* d_in, const int* in_sizes, int n_in,
                              void* d_out, int out_size, void* d_ws, size_t ws_size,
                              hipStream_t stream) {
  const float* x    = (const float*)d_in[0];
  const float* Wq   = (const float*)d_in[1];
  const float* Wk   = (const float*)d_in[2];
  const float* Wg1  = (const float*)d_in[3];
  const float* Wg2  = (const float*)d_in[4];
  const float* Wv   = (const float*)d_in[5];
  const float* Wgp  = (const float*)d_in[6];
  const float* bgp  = (const float*)d_in[7];
  const float* Wout = (const float*)d_in[8];
  float* out = (float*)d_out;

  char* ws = (char*)d_ws;
  float*  Y      = (float*)(ws + 0);                 // 25165824
  float*  Tt     = (float*)(ws + 25165824);          // 8388608
  ushort* Stb    = (ushort*)(ws + 33554432);         // 4194304
  float*  gamma  = (float*)(ws + 37748736);          // 65536
  float*  af     = (float*)(ws + 37814272);          // 65536
  float*  Atot   = (float*)(ws + 37879808);          // 1024
  ushort* Qb     = (ushort*)(ws + 37880832);         // 2097152
  ushort* Kb     = (ushort*)(ws + 39977984);         // 2097152
  ushort* Ktb    = (ushort*)(ws + 42075136);         // 2097152
  ushort* Vtb    = (ushort*)(ws + 44172288);         // 4194304
  ushort* xb     = (ushort*)(ws + 48366592);         // 4194304
  ushort* WcatT  = (ushort*)(ws + 52560896);         // 6291456
  ushort* WoutT  = (ushort*)(ws + 58852352);         // 2097152
  ushort* gout   = (ushort*)(ws + 60949504);         // 4194304
  // total 65143808 bytes

  cvt_bf16_kernel<<<2048, 256, 0, stream>>>(x, xb, 2048 * 1024 / 4);
  conv_T_kernel<<<dim3(16, 32), 256, 0, stream>>>(Wq,  WcatT + (size_t)0 * 1024,    1024, 512,  1.0f);
  conv_T_kernel<<<dim3(16, 32), 256, 0, stream>>>(Wk,  WcatT + (size_t)512 * 1024,  1024, 512,  0.125f);
  conv_T_kernel<<<dim3(32, 32), 256, 0, stream>>>(Wv,  WcatT + (size_t)1024 * 1024, 1024, 1024, 1.0f);
  conv_T_kernel<<<dim3(32, 32), 256, 0, stream>>>(Wgp, WcatT + (size_t)2048 * 1024, 1024, 1024, 1.0f);
  conv_T_kernel<<<dim3(32, 32), 256, 0, stream>>>(Wout, WoutT,                      1024, 1024, 1.0f);

  gate_kernel<<<2048, 256, 0, stream>>>(x, Wg1, Wg2, gamma);

  // fused projections: Y = xb @ [Wq|Wk*s|Wv|Wgp]
  gemm_bf16_kernel<<<dim3(16, 24), 256, 0, stream>>>(xb, WcatT, Y, 2048, 3072, 1024);

  // chunked scan (MFMA)
  prefix_kernel<<<256, 64, 0, stream>>>(gamma, af, Atot);
  prep_kernel<<<dim3(16, 16), 256, 0, stream>>>(Y, af, Atot, Qb, Kb, Ktb, Vtb);
  chunk_T_kernel<<<dim3(16, 16), 256, 0, stream>>>(Ktb, Vtb, Tt);
  state_kernel<<<dim3(16, 16), 256, 0, stream>>>(Tt, Atot, Stb);
  out_chunk_kernel<<<dim3(16, 16), 256, 0, stream>>>(Y, af, Qb, Kb, Stb, Vtb, bgp, gout);

  // output projection
  gemm_bf16_kernel<<<dim3(16, 8), 256, 0, stream>>>(gout, WoutT, out, 2048, 1024, 1024);
}

// Round 4
// 106.228 us; speedup vs baseline: 2.3989x; 1.0701x over previous
//
#include <hip/hip_runtime.h>

typedef __bf16 bf16x8 __attribute__((ext_vector_type(8)));
typedef float floatx4 __attribute__((ext_vector_type(4)));

__device__ __forceinline__ ushort f2bf(float f) {
  union { float f; unsigned u; } a; a.f = f;
  unsigned u = a.u;
  unsigned r = (u + 0x7FFFu + ((u >> 16) & 1u)) >> 16;
  return (ushort)r;
}

// async global->LDS, 16B per lane; lds base must be wave-uniform
__device__ __forceinline__ void gl_lds16(const ushort* g, ushort* l) {
  __builtin_amdgcn_global_load_lds((const __attribute__((address_space(1))) void*)g,
                                   (__attribute__((address_space(3))) void*)l, 16, 0, 0);
}

// swizzled index helpers (element index in, element index out)
#define SWZH(row, col, stride) ((((row) * (stride)) + (col)) ^ (((row) & 7) << 3))  // ushort tiles
#define SWZF(row, col, stride) ((((row) * (stride)) + (col)) ^ (((row) & 7) << 2))  // f32 tiles

// ---------------- fused weight conversions ----------------
// virtual col nv in [0,4096): [Wq | Wk*0.125 | Wv | Wgp] -> WcatT rows 0..3071,
// [Wout] -> WoutT rows 0..1023. All K=1024.
__global__ __launch_bounds__(256) void conv_all_kernel(
    const float* __restrict__ Wq, const float* __restrict__ Wk,
    const float* __restrict__ Wv, const float* __restrict__ Wgp,
    const float* __restrict__ Wout,
    ushort* __restrict__ WcatT, ushort* __restrict__ WoutT) {
  int nv = blockIdx.x * 32, k0 = blockIdx.y * 32;
  const float* W; ushort* dst; int N, ncol, nrow; float scale = 1.f;
  if (nv < 512)       { W = Wq;   N = 512;  ncol = nv;         nrow = nv;        dst = WcatT; }
  else if (nv < 1024) { W = Wk;   N = 512;  ncol = nv - 512;   nrow = nv;        dst = WcatT; scale = 0.125f; }
  else if (nv < 2048) { W = Wv;   N = 1024; ncol = nv - 1024;  nrow = nv;        dst = WcatT; }
  else if (nv < 3072) { W = Wgp;  N = 1024; ncol = nv - 2048;  nrow = nv;        dst = WcatT; }
  else                { W = Wout; N = 1024; ncol = nv - 3072;  nrow = nv - 3072; dst = WoutT; }
  __shared__ float tile[32][33];
  int xi = threadIdx.x & 31, yi = threadIdx.x >> 5;
  #pragma unroll
  for (int i = 0; i < 32; i += 8)
    tile[yi + i][xi] = W[(size_t)(k0 + yi + i) * N + ncol + xi];
  __syncthreads();
  #pragma unroll
  for (int i = 0; i < 32; i += 8)
    dst[(size_t)(nrow + yi + i) * 1024 + k0 + xi] = f2bf(tile[xi][yi + i] * scale);
}

// ---------------- GEMM: C(MxN,f32) = A(MxK,bf16) * BT(NxK,bf16)^T ----------------
// 128x128 tile, BK=64, 4 waves, global_load_lds staging (m97 structure)
__global__ __launch_bounds__(256) void gemm_bf16_kernel(const ushort* __restrict__ A,
                                                        const ushort* __restrict__ BT,
                                                        float* __restrict__ C,
                                                        int M, int N, int K) {
  __shared__ __align__(16) ushort As[128 * 64];
  __shared__ __align__(16) ushort Bs[128 * 64];
  int tid = threadIdx.x;
  int lane = tid & 63, wid = tid >> 6;
  int wr = wid >> 1, wc = wid & 1;
  int m0 = blockIdx.x * 128, n0 = blockIdx.y * 128;
  int row = lane & 15, kseg = (lane >> 4) << 3;

  floatx4 acc[4][4];
  #pragma unroll
  for (int r = 0; r < 4; r++)
    #pragma unroll
    for (int c = 0; c < 4; c++)
      acc[r][c] = (floatx4){0.f, 0.f, 0.f, 0.f};

  // staging: wave w covers tile rows [w*32, w*32+32); lane l -> row +(l>>3), col (l&7)*8
  int srow = wid * 32 + (lane >> 3);
  int scol = (lane & 7) * 8;
  const ushort* ag = A + (size_t)(m0 + srow) * K + scol;
  const ushort* bg = BT + (size_t)(n0 + srow) * K + scol;
  ushort* asb = As + (wid * 32) * 64;  // wave-uniform LDS bases
  ushort* bsb = Bs + (wid * 32) * 64;

  for (int k0 = 0; k0 < K; k0 += 64) {
    __syncthreads();  // previous iteration's LDS readers done
    #pragma unroll
    for (int i = 0; i < 4; i++) {
      gl_lds16(ag + (size_t)(i * 8) * K + k0, asb + i * 8 * 64);
      gl_lds16(bg + (size_t)(i * 8) * K + k0, bsb + i * 8 * 64);
    }
    __syncthreads();  // vmcnt(0) drain + barrier -> tiles visible
    #pragma unroll
    for (int kk = 0; kk < 64; kk += 32) {
      bf16x8 av[4], bv[4];
      #pragma unroll
      for (int r = 0; r < 4; r++)
        av[r] = *(const bf16x8*)&As[(wr * 64 + r * 16 + row) * 64 + kk + kseg];
      #pragma unroll
      for (int c = 0; c < 4; c++)
        bv[c] = *(const bf16x8*)&Bs[(wc * 64 + c * 16 + row) * 64 + kk + kseg];
      #pragma unroll
      for (int r = 0; r < 4; r++)
        #pragma unroll
        for (int c = 0; c < 4; c++)
          acc[r][c] = __builtin_amdgcn_mfma_f32_16x16x32_bf16(av[r], bv[c], acc[r][c], 0, 0, 0);
    }
  }

  int r4 = (lane >> 4) << 2;
  #pragma unroll
  for (int r = 0; r < 4; r++)
    #pragma unroll
    for (int c = 0; c < 4; c++) {
      int crow = m0 + wr * 64 + r * 16 + r4;
      int ccol = n0 + wc * 64 + c * 16 + (lane & 15);
      #pragma unroll
      for (int i = 0; i < 4; i++)
        C[(size_t)(crow + i) * N + ccol] = acc[r][c][i];
    }
}

// ---------------- decay gate (full f32) + x->bf16 conversion ----------------
__global__ __launch_bounds__(256) void gate_kernel(const float* __restrict__ x,
                                                   const float* __restrict__ Wg1,
                                                   const float* __restrict__ Wg2,
                                                   float* __restrict__ gamma,
                                                   ushort* __restrict__ xb) {
  int rowi = blockIdx.x;          // b*1024 + l
  int b = rowi >> 10, l = rowi & 1023;
  int tid = threadIdx.x;
  __shared__ float part[16][17];
  __shared__ float tsh[16];

  // fused: convert this x row to bf16 (coalesced float4 read)
  {
    float4 v = *(const float4*)(x + (size_t)rowi * 1024 + tid * 4);
    ushort4 o;
    o.x = f2bf(v.x); o.y = f2bf(v.y); o.z = f2bf(v.z); o.w = f2bf(v.w);
    *(ushort4*)(xb + (size_t)rowi * 1024 + tid * 4) = o;
  }

  {
    int j = tid & 15, slice = tid >> 4;
    const float* xr = x + (size_t)rowi * 1024 + slice * 64;
    float p = 0.f;
    #pragma unroll 4
    for (int kk = 0; kk < 64; kk++)
      p += xr[kk] * Wg1[(size_t)(slice * 64 + kk) * 16 + j];
    part[slice][j] = p;
  }
  __syncthreads();
  if (tid < 16) {
    float s = 0.f;
    #pragma unroll
    for (int i = 0; i < 16; i++) s += part[i][tid];
    tsh[tid] = s;
  }
  __syncthreads();

  float ls0, ls1;
  {
    int n = tid;
    float kg = 0.f;
    #pragma unroll
    for (int j = 0; j < 16; j++) kg += tsh[j] * Wg2[j * 512 + n];
    ls0 = (kg >= 0.f) ? -log1pf(expf(-kg)) : (kg - log1pf(expf(kg)));
  }
  {
    int n = tid + 256;
    float kg = 0.f;
    #pragma unroll
    for (int j = 0; j < 16; j++) kg += tsh[j] * Wg2[j * 512 + n];
    ls1 = (kg >= 0.f) ? -log1pf(expf(-kg)) : (kg - log1pf(expf(kg)));
  }
  #pragma unroll
  for (int m = 32; m >= 1; m >>= 1) {
    ls0 += __shfl_xor(ls0, m);
    ls1 += __shfl_xor(ls1, m);
  }
  if ((tid & 63) == 0) {
    int w = tid >> 6;
    gamma[(size_t)(b * 8 + w) * 1024 + l]       = expf(ls0 * (1.f / 1024.f)) + 1e-6f;
    gamma[(size_t)(b * 8 + w + 4) * 1024 + l]   = expf(ls1 * (1.f / 1024.f)) + 1e-6f;
  }
}

// ---------------- within-chunk prefix products ----------------
__global__ __launch_bounds__(64) void prefix_kernel(const float* __restrict__ gamma,
                                                    float* __restrict__ af,
                                                    float* __restrict__ Atot) {
  int blk = blockIdx.x;
  int bh = blk >> 4, c = blk & 15;
  int lane = threadIdx.x;
  float g = gamma[(size_t)bh * 1024 + c * 64 + lane];
  #pragma unroll
  for (int m = 1; m < 64; m <<= 1) {
    float o = __shfl_up(g, m);
    if (lane >= m) g *= o;
  }
  af[(size_t)bh * 1024 + c * 64 + lane] = g;
  if (lane == 63) Atot[blk] = g;
}

// ---------------- prep: bf16 operand arrays ----------------
// Qb[bh][l][d] = a_l * q ;  Kb[bh][l][d] = k ;  Ktb[bh][d][l] = (Ac/a_l) * k ;
// Vtb[bh][e][l] = v
__global__ __launch_bounds__(256) void prep_kernel(const float* __restrict__ Y,
                                                   const float* __restrict__ af,
                                                   const float* __restrict__ Atot,
                                                   ushort* __restrict__ Qb,
                                                   ushort* __restrict__ Kb,
                                                   ushort* __restrict__ Ktb,
                                                   ushort* __restrict__ Vtb) {
  int c = blockIdx.x, bh = blockIdx.y;
  int b = bh >> 3, h = bh & 7;
  int tid = threadIdx.x;
  __shared__ float a_sh[64];
  __shared__ __align__(16) float tile[64 * 68];

  float Ac = Atot[bh * 16 + c];
  if (tid < 64) a_sh[tid] = af[(size_t)bh * 1024 + c * 64 + tid];
  __syncthreads();

  const float* Yc = Y + (size_t)(b * 1024 + c * 64) * 3072;

  #pragma unroll
  for (int i = 0; i < 4; i++) {
    int u = tid + i * 256;
    int row = u >> 4, col4 = u & 15;
    float at = a_sh[row];
    float4 q4 = *(const float4*)(Yc + (size_t)row * 3072 + h * 64 + col4 * 4);
    float4 k4 = *(const float4*)(Yc + (size_t)row * 3072 + 512 + h * 64 + col4 * 4);
    ushort4 qo, ko;
    qo.x = f2bf(q4.x * at); qo.y = f2bf(q4.y * at); qo.z = f2bf(q4.z * at); qo.w = f2bf(q4.w * at);
    ko.x = f2bf(k4.x); ko.y = f2bf(k4.y); ko.z = f2bf(k4.z); ko.w = f2bf(k4.w);
    *(ushort4*)(Qb + ((size_t)(bh * 1024 + c * 64 + row)) * 64 + col4 * 4) = qo;
    *(ushort4*)(Kb + ((size_t)(bh * 1024 + c * 64 + row)) * 64 + col4 * 4) = ko;
    *(float4*)&tile[row * 68 + col4 * 4] = k4;
  }
  __syncthreads();

  {
    int d = tid & 63, sb = tid >> 6;
    ushort o[16];
    #pragma unroll
    for (int j = 0; j < 16; j++) {
      int s = sb * 16 + j;
      o[j] = f2bf(tile[s * 68 + d] * (Ac / a_sh[s]));
    }
    ushort* dst = Ktb + ((size_t)(bh * 64 + d)) * 1024 + c * 64 + sb * 16;
    *(uint4*)(dst) = *(uint4*)&o[0];
    *(uint4*)(dst + 8) = *(uint4*)&o[8];
  }

  #pragma unroll
  for (int p = 0; p < 2; p++) {
    __syncthreads();
    #pragma unroll
    for (int i = 0; i < 4; i++) {
      int u = tid + i * 256;
      int row = u >> 4, col4 = u & 15;
      *(float4*)&tile[row * 68 + col4 * 4] =
          *(const float4*)(Yc + (size_t)row * 3072 + 1024 + h * 128 + p * 64 + col4 * 4);
    }
    __syncthreads();
    {
      int el = tid & 63, sb = tid >> 6;
      ushort o[16];
      #pragma unroll
      for (int j = 0; j < 16; j++)
        o[j] = f2bf(tile[(sb * 16 + j) * 68 + el]);
      ushort* dst = Vtb + ((size_t)(bh * 128 + p * 64 + el)) * 1024 + c * 64 + sb * 16;
      *(uint4*)(dst) = *(uint4*)&o[0];
      *(uint4*)(dst + 8) = *(uint4*)&o[8];
    }
  }
}

// ---------------- per-chunk Tt[e][d] = sum_s V[s][e] * w_s k[s][d]  (MFMA) ----------------
__global__ __launch_bounds__(256) void chunk_T_kernel(const ushort* __restrict__ Ktb,
                                                      const ushort* __restrict__ Vtb,
                                                      float* __restrict__ Tt) {
  int c = blockIdx.x, bh = blockIdx.y;
  int tid = threadIdx.x;
  int lane = tid & 63, wid = tid >> 6;
  int col_l = lane & 15, kseg8 = (lane >> 4) * 8;
  int d0w = wid * 16;

  __shared__ __align__(16) ushort Kt[64 * 64];
  __shared__ __align__(16) ushort Vs[128 * 64];

  #pragma unroll
  for (int i = 0; i < 2; i++) {
    int u = tid + i * 256;
    int row = u >> 3, col8 = u & 7;
    *(uint4*)&Kt[SWZH(row, col8 * 8, 64)] =
        *(const uint4*)(Ktb + ((size_t)(bh * 64 + row)) * 1024 + c * 64 + col8 * 8);
  }
  #pragma unroll
  for (int i = 0; i < 4; i++) {
    int u = tid + i * 256;
    int row = u >> 3, col8 = u & 7;
    *(uint4*)&Vs[SWZH(row, col8 * 8, 64)] =
        *(const uint4*)(Vtb + ((size_t)(bh * 128 + row)) * 1024 + c * 64 + col8 * 8);
  }
  __syncthreads();

  floatx4 acc[8];
  #pragma unroll
  for (int i = 0; i < 8; i++) acc[i] = (floatx4){0.f, 0.f, 0.f, 0.f};

  #pragma unroll
  for (int kk = 0; kk < 64; kk += 32) {
    bf16x8 kb = *(const bf16x8*)&Kt[SWZH(d0w + col_l, kk + kseg8, 64)];
    #pragma unroll
    for (int fe = 0; fe < 8; fe++) {
      bf16x8 vb = *(const bf16x8*)&Vs[SWZH(fe * 16 + col_l, kk + kseg8, 64)];
      acc[fe] = __builtin_amdgcn_mfma_f32_16x16x32_bf16(vb, kb, acc[fe], 0, 0, 0);
    }
  }

  float* To = Tt + (size_t)(bh * 16 + c) * 8192;
  #pragma unroll
  for (int fe = 0; fe < 8; fe++) {
    #pragma unroll
    for (int r = 0; r < 4; r++) {
      int e = fe * 16 + (lane >> 4) * 4 + r;
      To[(size_t)e * 64 + d0w + col_l] = acc[fe][r];
    }
  }
}

// ---------------- inter-chunk state recurrence (e-sliced) ----------------
__global__ __launch_bounds__(256) void state_kernel(const float* __restrict__ Tt,
                                                    const float* __restrict__ Atot,
                                                    ushort* __restrict__ Stb) {
  int es = blockIdx.x, bh = blockIdx.y;
  int tid = threadIdx.x;
  size_t off = (size_t)es * 512 + tid * 2;
  float2 S = {0.f, 0.f};
  for (int c = 0; c < 16; c++) {
    float A = Atot[bh * 16 + c];
    size_t base = (size_t)(bh * 16 + c) * 8192 + off;
    ushort2 o; o.x = f2bf(S.x); o.y = f2bf(S.y);
    *(ushort2*)(Stb + base) = o;
    float2 t = *(const float2*)(Tt + base);
    S.x = A * S.x + t.x;
    S.y = A * S.y + t.y;
  }
}

// ---------------- per-chunk output (MFMA) + LN + silu gate -> bf16 ----------------
__global__ __launch_bounds__(256) void out_chunk_kernel(const float* __restrict__ Y,
                                                        const float* __restrict__ af,
                                                        const ushort* __restrict__ Qb,
                                                        const ushort* __restrict__ Kb,
                                                        const ushort* __restrict__ Stb,
                                                        const ushort* __restrict__ Vtb,
                                                        const float* __restrict__ bgp,
                                                        ushort* __restrict__ gout) {
  int c = blockIdx.x, bh = blockIdx.y;
  int b = bh >> 3, h = bh & 7;
  int tid = threadIdx.x;
  int lane = tid & 63, wid = tid >> 6;
  int col_l = lane & 15, kseg8 = (lane >> 4) * 8;
  int t0w = wid * 16;

  __shared__ __align__(16) ushort Qs[64 * 64];
  __shared__ __align__(16) ushort Ks[64 * 64];
  __shared__ __align__(16) ushort Ss[128 * 64];
  __shared__ __align__(16) ushort Vs[128 * 64];
  __shared__ __align__(16) ushort Ps[64 * 64];
  __shared__ __align__(16) float zs[64 * 128];
  __shared__ float inva_sh[64];
  __shared__ float bsh[128];

  const float* Yc = Y + (size_t)(b * 1024 + c * 64) * 3072;

  #pragma unroll
  for (int i = 0; i < 2; i++) {
    int u = tid + i * 256;
    int row = u >> 3, col8 = u & 7;
    *(uint4*)&Qs[SWZH(row, col8 * 8, 64)] =
        *(const uint4*)(Qb + ((size_t)(bh * 1024 + c * 64 + row)) * 64 + col8 * 8);
    *(uint4*)&Ks[SWZH(row, col8 * 8, 64)] =
        *(const uint4*)(Kb + ((size_t)(bh * 1024 + c * 64 + row)) * 64 + col8 * 8);
  }
  #pragma unroll
  for (int i = 0; i < 4; i++) {
    int u = tid + i * 256;
    int row = u >> 3, col8 = u & 7;
    *(uint4*)&Ss[SWZH(row, col8 * 8, 64)] =
        *(const uint4*)(Stb + (size_t)(bh * 16 + c) * 8192 + (size_t)row * 64 + col8 * 8);
    *(uint4*)&Vs[SWZH(row, col8 * 8, 64)] =
        *(const uint4*)(Vtb + ((size_t)(bh * 128 + row)) * 1024 + c * 64 + col8 * 8);
  }
  #pragma unroll
  for (int i = 0; i < 8; i++) {
    int u = tid + i * 256;
    int row = u >> 5, col4 = u & 31;
    *(float4*)&zs[SWZF(row, col4 * 4, 128)] =
        *(const float4*)(Yc + (size_t)row * 3072 + 2048 + h * 128 + col4 * 4);
  }
  if (tid < 64) inva_sh[tid] = 1.f / af[(size_t)bh * 1024 + c * 64 + tid];
  if (tid < 128) bsh[tid] = bgp[h * 128 + tid];
  __syncthreads();

  floatx4 pacc[4];
  floatx4 acc[8];
  #pragma unroll
  for (int i = 0; i < 4; i++) pacc[i] = (floatx4){0.f, 0.f, 0.f, 0.f};
  #pragma unroll
  for (int i = 0; i < 8; i++) acc[i] = (floatx4){0.f, 0.f, 0.f, 0.f};

  #pragma unroll
  for (int kk = 0; kk < 64; kk += 32) {
    bf16x8 qb = *(const bf16x8*)&Qs[SWZH(t0w + col_l, kk + kseg8, 64)];
    #pragma unroll
    for (int fs = 0; fs < 4; fs++) {
      bf16x8 kb = *(const bf16x8*)&Ks[SWZH(fs * 16 + col_l, kk + kseg8, 64)];
      pacc[fs] = __builtin_amdgcn_mfma_f32_16x16x32_bf16(kb, qb, pacc[fs], 0, 0, 0);
    }
    #pragma unroll
    for (int fe = 0; fe < 8; fe++) {
      bf16x8 sb = *(const bf16x8*)&Ss[SWZH(fe * 16 + col_l, kk + kseg8, 64)];
      acc[fe] = __builtin_amdgcn_mfma_f32_16x16x32_bf16(sb, qb, acc[fe], 0, 0, 0);
    }
  }

  int tl = t0w + col_l;
  #pragma unroll
  for (int fs = 0; fs < 4; fs++) {
    ushort o[4];
    #pragma unroll
    for (int r = 0; r < 4; r++) {
      int s = fs * 16 + (lane >> 4) * 4 + r;
      float pv = (s <= tl) ? pacc[fs][r] * inva_sh[s] : 0.f;
      o[r] = f2bf(pv);
    }
    int s0 = fs * 16 + (lane >> 4) * 4;
    *(ushort4*)&Ps[SWZH(tl, s0, 64)] = *(ushort4*)&o[0];
  }
  __syncthreads();

  #pragma unroll
  for (int kk = 0; kk < 64; kk += 32) {
    bf16x8 pb = *(const bf16x8*)&Ps[SWZH(t0w + col_l, kk + kseg8, 64)];
    #pragma unroll
    for (int fe = 0; fe < 8; fe++) {
      bf16x8 vb = *(const bf16x8*)&Vs[SWZH(fe * 16 + col_l, kk + kseg8, 64)];
      acc[fe] = __builtin_amdgcn_mfma_f32_16x16x32_bf16(vb, pb, acc[fe], 0, 0, 0);
    }
  }
  __syncthreads();

  float s1 = 0.f, s2 = 0.f;
  #pragma unroll
  for (int fe = 0; fe < 8; fe++)
    #pragma unroll
    for (int r = 0; r < 4; r++) {
      float v = acc[fe][r];
      s1 += v; s2 += v * v;
    }
  s1 += __shfl_xor(s1, 16); s2 += __shfl_xor(s2, 16);
  s1 += __shfl_xor(s1, 32); s2 += __shfl_xor(s2, 32);
  float mu = s1 * (1.f / 128.f);
  float var = s2 * (1.f / 128.f) - mu * mu;
  float rs = rsqrtf(var + 1e-5f);

  ushort* Gs = Vs;  // reuse
  #pragma unroll
  for (int fe = 0; fe < 8; fe++)
    #pragma unroll
    for (int r = 0; r < 4; r++) {
      int e = fe * 16 + (lane >> 4) * 4 + r;
      float y = (acc[fe][r] - mu) * rs;
      float z = zs[SWZF(tl, e, 128)] + bsh[e];
      float g = z / (1.f + expf(-z));
      Gs[SWZH(tl, e, 128)] = f2bf(y * g);
    }
  __syncthreads();

  #pragma unroll
  for (int i = 0; i < 4; i++) {
    int u = tid + i * 256;
    int row = u >> 4, ch = u & 15;
    *(uint4*)(gout + ((size_t)(b * 1024 + c * 64 + row)) * 1024 + h * 128 + ch * 8) =
        *(uint4*)&Gs[SWZH(row, ch * 8, 128)];
  }
}

// ---------------- launch ----------------
extern "C" void kernel_launch(void* const* d_in, const int* in_sizes, int n_in,
                              void* d_out, int out_size, void* d_ws, size_t ws_size,
                              hipStream_t stream) {
  const float* x    = (const float*)d_in[0];
  const float* Wq   = (const float*)d_in[1];
  const float* Wk   = (const float*)d_in[2];
  const float* Wg1  = (const float*)d_in[3];
  const float* Wg2  = (const float*)d_in[4];
  const float* Wv   = (const float*)d_in[5];
  const float* Wgp  = (const float*)d_in[6];
  const float* bgp  = (const float*)d_in[7];
  const float* Wout = (const float*)d_in[8];
  float* out = (float*)d_out;

  char* ws = (char*)d_ws;
  float*  Y      = (float*)(ws + 0);                 // 25165824
  float*  Tt     = (float*)(ws + 25165824);          // 8388608
  ushort* Stb    = (ushort*)(ws + 33554432);         // 4194304
  float*  gamma  = (float*)(ws + 37748736);          // 65536
  float*  af     = (float*)(ws + 37814272);          // 65536
  float*  Atot   = (float*)(ws + 37879808);          // 1024
  ushort* Qb     = (ushort*)(ws + 37880832);         // 2097152
  ushort* Kb     = (ushort*)(ws + 39977984);         // 2097152
  ushort* Ktb    = (ushort*)(ws + 42075136);         // 2097152
  ushort* Vtb    = (ushort*)(ws + 44172288);         // 4194304
  ushort* xb     = (ushort*)(ws + 48366592);         // 4194304
  ushort* WcatT  = (ushort*)(ws + 52560896);         // 6291456
  ushort* WoutT  = (ushort*)(ws + 58852352);         // 2097152
  ushort* gout   = (ushort*)(ws + 60949504);         // 4194304
  // total 65143808 bytes

  // fused conversions: all five weights in one launch; x->bf16 inside gate_kernel
  conv_all_kernel<<<dim3(128, 32), 256, 0, stream>>>(Wq, Wk, Wv, Wgp, Wout, WcatT, WoutT);
  gate_kernel<<<2048, 256, 0, stream>>>(x, Wg1, Wg2, gamma, xb);

  // fused projections: Y = xb @ [Wq|Wk*s|Wv|Wgp]
  gemm_bf16_kernel<<<dim3(16, 24), 256, 0, stream>>>(xb, WcatT, Y, 2048, 3072, 1024);

  // chunked scan (MFMA)
  prefix_kernel<<<256, 64, 0, stream>>>(gamma, af, Atot);
  prep_kernel<<<dim3(16, 16), 256, 0, stream>>>(Y, af, Atot, Qb, Kb, Ktb, Vtb);
  chunk_T_kernel<<<dim3(16, 16), 256, 0, stream>>>(Ktb, Vtb, Tt);
  state_kernel<<<dim3(16, 16), 256, 0, stream>>>(Tt, Atot, Stb);
  out_chunk_kernel<<<dim3(16, 16), 256, 0, stream>>>(Y, af, Qb, Kb, Stb, Vtb, bgp, gout);

  // output projection
  gemm_bf16_kernel<<<dim3(16, 8), 256, 0, stream>>>(gout, WoutT, out, 2048, 1024, 1024);
}